// Round 1
// baseline (612.408 us; speedup 1.0000x reference)
//
#include <hip/hip_runtime.h>
#include <hip/hip_bf16.h>
#include <stdint.h>

typedef __bf16 bf16;
typedef bf16 bf16x8 __attribute__((ext_vector_type(8)));
typedef float f32x4 __attribute__((ext_vector_type(4)));

// ---------------------------------------------------------------------------
// Workspace layout (bytes):
//   fbf   @ 0        : [65536][64] bf16 (f padded, slot57=1.0)   8,388,608
//   O1T   @ 8388608  : [54][128][64] bf16 (perm c, bias@k=57)      884,736
//   O2T   @ 9273344  : [54][3][128] bf16                            41,472
//   Cw1T  @ 9314816  : [128][4]  f32                                 2,048
//   Nw1T  @ 9316864  : [128][56] f32 (pad 0)                        28,672
//   Fw1T  @ 9345536  : [128][60] f32 (pad 0)                        30,720
//   Cw2p  @ 9376256  : [128][4]  f32 (pad 0)                         2,048
//   Nw2p  @ 9378304  : [128][56] f32 (pad 0)                        28,672
//   Fw2p  @ 9406976  : [128][60] f32 (pad 0)                        30,720
//   total ~9.44 MB
// ---------------------------------------------------------------------------

__global__ __launch_bounds__(256) void prep_kernel(
    const float* __restrict__ Ow1, const float* __restrict__ Ob1,
    const float* __restrict__ Ow2,
    const float* __restrict__ Cw1, const float* __restrict__ Nw1,
    const float* __restrict__ Fw1, const float* __restrict__ Cw2,
    const float* __restrict__ Nw2, const float* __restrict__ Fw2,
    bf16* __restrict__ O1T, bf16* __restrict__ O2T,
    float* __restrict__ Cw1T, float* __restrict__ Nw1T, float* __restrict__ Fw1T,
    float* __restrict__ Cw2p, float* __restrict__ Nw2p, float* __restrict__ Fw2p)
{
  int gid = blockIdx.x * 256 + threadIdx.x;
  // Task 1: O1T[br][m][k] = Ow1[br][k][sigma(m)] (k<57), Ob1[br][sigma(m)] (k==57), 0 else.
  // sigma(m): bit-permute so layer1 D-frag regs are layer2 B-frag k-slices:
  //   c = 32*(m>>5) | 8*((m>>2)&3) | 4*((m>>4)&1) | (m&3)
  if (gid < 442368) {
    int k  = gid & 63;
    int m  = (gid >> 6) & 127;
    int br = gid >> 13;
    int c  = ((m >> 5) << 5) | (((m >> 2) & 3) << 3) | (((m >> 4) & 1) << 2) | (m & 3);
    float v = 0.f;
    if (k < 57)       v = Ow1[(br * 57 + k) * 128 + c];
    else if (k == 57) v = Ob1[br * 128 + c];
    O1T[gid] = (bf16)v;
    return;
  }
  gid -= 442368;
  // Task 2: O2T[br][e][c] = Ow2[br][c][e]
  if (gid < 20736) {
    int br  = gid / 384;
    int rem = gid - br * 384;
    int e   = rem >> 7;
    int cc  = rem & 127;
    O2T[gid] = (bf16)Ow2[(br * 128 + cc) * 3 + e];
    return;
  }
  gid -= 20736;
  if (gid < 512)  { int j = gid >> 2, i = gid & 3;      Cw1T[gid] = Cw1[i * 128 + j]; return; }
  gid -= 512;
  if (gid < 7168) { int j = gid / 56, i = gid - j * 56; Nw1T[gid] = (i < 54) ? Nw1[i * 128 + j] : 0.f; return; }
  gid -= 7168;
  if (gid < 7680) { int j = gid / 60, i = gid - j * 60; Fw1T[gid] = (i < 57) ? Fw1[i * 128 + j] : 0.f; return; }
  gid -= 7680;
  if (gid < 512)  { int j = gid >> 2, e = gid & 3;      Cw2p[gid] = (e < 3) ? Cw2[j * 3 + e] : 0.f; return; }
  gid -= 512;
  if (gid < 7168) { int j = gid / 56, o = gid - j * 56; Nw2p[gid] = (o < 54) ? Nw2[j * 54 + o] : 0.f; return; }
  gid -= 7168;
  if (gid < 7680) { int j = gid / 60, o = gid - j * 60; Fw2p[gid] = (o < 57) ? Fw2[j * 57 + o] : 0.f; return; }
}

// ---------------------------------------------------------------------------
// Kernel 1: exact fp32 C/N/F MLPs. Thread-per-row, 2-way j-split per block.
// Block = 256 thr = 128 rows x 2 j-halves. Weights at wave-uniform addresses.
// ---------------------------------------------------------------------------
__global__ __launch_bounds__(256) void mlp_cnf_kernel(
    const float* __restrict__ x,
    const float* __restrict__ Cw1T, const float* __restrict__ Cb1,
    const float* __restrict__ Cw2p, const float* __restrict__ Cb2,
    const float* __restrict__ Nw1T, const float* __restrict__ Nb1,
    const float* __restrict__ Nw2p, const float* __restrict__ Nb2,
    const float* __restrict__ Fw1T, const float* __restrict__ Fb1,
    const float* __restrict__ Fw2p, const float* __restrict__ Fb2,
    bf16* __restrict__ fbf)
{
  __shared__ float sh[128][59];   // stride 59 (gcd(59,32)=1) -> conflict-free-ish
  const int tid  = threadIdx.x;
  const int r    = tid & 127;
  const int half = tid >> 7;      // wave-uniform
  const int row  = blockIdx.x * 128 + r;

  // load x[row][0..57] via float2 (row*232B is 8B aligned)
  float xv[58];
  const float2* x2 = (const float2*)(x + row * 58);
#pragma unroll
  for (int q = 0; q < 29; ++q) { float2 t = x2[q]; xv[2*q] = t.x; xv[2*q+1] = t.y; }

  // ---- C branch (both halves compute full; bitwise identical) ----
  float c0 = Cb2[0], c1 = Cb2[1], c2 = Cb2[2];
#pragma unroll 4
  for (int j = 0; j < 128; ++j) {
    const float4 w1 = *(const float4*)(Cw1T + j * 4);
    float hj = Cb1[j] + xv[0]*w1.x + xv[1]*w1.y + xv[2]*w1.z + xv[3]*w1.w;
    hj = fmaxf(hj, 0.f);
    const float4 w2 = *(const float4*)(Cw2p + j * 4);
    c0 += hj * w2.x; c1 += hj * w2.y; c2 += hj * w2.z;
  }

  // ---- N branch, split over j ----
  float nacc[56];
#pragma unroll
  for (int o = 0; o < 56; ++o) nacc[o] = 0.f;
  if (half == 0) {
#pragma unroll
    for (int o = 0; o < 54; ++o) nacc[o] = Nb2[o];
  }
  const int jbase = __builtin_amdgcn_readfirstlane(half * 64);
#pragma unroll 2
  for (int jj = 0; jj < 64; ++jj) {
    const int j = jbase + jj;
    const float* w1r = Nw1T + j * 56;
    float h0 = 0, h1 = 0, h2 = 0, h3 = 0;
#pragma unroll
    for (int q = 0; q < 13; ++q) {
      float4 w = *(const float4*)(w1r + q * 4);
      h0 += xv[4+4*q]*w.x; h1 += xv[5+4*q]*w.y; h2 += xv[6+4*q]*w.z; h3 += xv[7+4*q]*w.w;
    }
    { float2 w = *(const float2*)(w1r + 52); h0 += xv[56]*w.x; h1 += xv[57]*w.y; }
    float hj = fmaxf(h0 + h1 + h2 + h3 + Nb1[j], 0.f);
    const float* w2r = Nw2p + j * 56;
#pragma unroll
    for (int q = 0; q < 14; ++q) {
      float4 w = *(const float4*)(w2r + q * 4);
      nacc[4*q] += hj*w.x; nacc[4*q+1] += hj*w.y; nacc[4*q+2] += hj*w.z; nacc[4*q+3] += hj*w.w;
    }
  }
  // combine n (half1 -> half0), then publish full n (half0 -> half1)
  if (half == 1) {
#pragma unroll
    for (int o = 0; o < 54; ++o) sh[r][o] = nacc[o];
  }
  __syncthreads();
  if (half == 0) {
#pragma unroll
    for (int o = 0; o < 54; ++o) nacc[o] += sh[r][o];
  }
  __syncthreads();
  if (half == 0) {
#pragma unroll
    for (int o = 0; o < 54; ++o) sh[r][o] = nacc[o];
  }
  __syncthreads();
  if (half == 1) {
#pragma unroll
    for (int o = 0; o < 54; ++o) nacc[o] = sh[r][o];
  }

  // ---- F branch, split over j ----
  float cn[60];
  cn[0] = c0; cn[1] = c1; cn[2] = c2;
#pragma unroll
  for (int o = 0; o < 54; ++o) cn[3 + o] = nacc[o];
  cn[57] = 0.f; cn[58] = 0.f; cn[59] = 0.f;
  float facc[60];
#pragma unroll
  for (int o = 0; o < 60; ++o) facc[o] = 0.f;
  if (half == 0) {
#pragma unroll
    for (int o = 0; o < 57; ++o) facc[o] = Fb2[o];
  }
#pragma unroll 2
  for (int jj = 0; jj < 64; ++jj) {
    const int j = jbase + jj;
    const float* w1r = Fw1T + j * 60;
    float h0 = 0, h1 = 0, h2 = 0, h3 = 0;
#pragma unroll
    for (int q = 0; q < 15; ++q) {
      float4 w = *(const float4*)(w1r + q * 4);
      h0 += cn[4*q]*w.x; h1 += cn[4*q+1]*w.y; h2 += cn[4*q+2]*w.z; h3 += cn[4*q+3]*w.w;
    }
    float hj = fmaxf(h0 + h1 + h2 + h3 + Fb1[j], 0.f);
    const float* w2r = Fw2p + j * 60;
#pragma unroll
    for (int q = 0; q < 15; ++q) {
      float4 w = *(const float4*)(w2r + q * 4);
      facc[4*q] += hj*w.x; facc[4*q+1] += hj*w.y; facc[4*q+2] += hj*w.z; facc[4*q+3] += hj*w.w;
    }
  }
  // combine f and store bf16 row (padded to 64, slot57=1.0 for bias trick)
  if (half == 1) {
#pragma unroll
    for (int o = 0; o < 57; ++o) sh[r][o] = facc[o];
  }
  __syncthreads();
  if (half == 0) {
#pragma unroll
    for (int o = 0; o < 57; ++o) facc[o] += sh[r][o];
    uint32_t wds[32];
#pragma unroll
    for (int q = 0; q < 28; ++q) {
      uint16_t lo = __builtin_bit_cast(uint16_t, (bf16)facc[2*q]);
      uint16_t hi = __builtin_bit_cast(uint16_t, (bf16)facc[2*q+1]);
      wds[q] = (uint32_t)lo | ((uint32_t)hi << 16);
    }
    {
      uint16_t lo = __builtin_bit_cast(uint16_t, (bf16)facc[56]);
      uint16_t hi = __builtin_bit_cast(uint16_t, (bf16)1.0f);
      wds[28] = (uint32_t)lo | ((uint32_t)hi << 16);
    }
    wds[29] = 0u; wds[30] = 0u; wds[31] = 0u;
    uint4* dst = (uint4*)(fbf + row * 64);
#pragma unroll
    for (int q = 0; q < 8; ++q) dst[q] = make_uint4(wds[4*q], wds[4*q+1], wds[4*q+2], wds[4*q+3]);
  }
}

// ---------------------------------------------------------------------------
// Kernel 2: 54 heads via bf16 MFMA (transposed formulation).
// Block = 256 thr = 4 waves, each wave owns 16 rows. Grid = 1024.
// Layer1: D1[m][r] = sum_k O1T[m][k]*f[r][k]  (16 MFMAs, K=64, bias in k=57)
// sigma-permutation makes D1 regs directly the layer2 B-frag k-slices.
// Layer2: D2[e][r] = sum_c W2T[e][c]*h[c][r]  (4 MFMAs, M=16 pad from 3)
// Logits end up lane-local in g==0 lanes -> per-lane softmax, 3 dword stores.
// ---------------------------------------------------------------------------
__global__ __launch_bounds__(256, 3) void heads_kernel(
    const bf16* __restrict__ fbf, const bf16* __restrict__ O1T,
    const bf16* __restrict__ O2Tg, const float* __restrict__ Ob2,
    float* __restrict__ out)
{
  __shared__ bf16 w2s[54 * 3 * 128];   // 41,472 B
  const int tid = threadIdx.x;
  {
    const uint32_t* src = (const uint32_t*)O2Tg;
    uint32_t* dst = (uint32_t*)w2s;
    for (int t = tid; t < 54 * 3 * 128 / 2; t += 256) dst[t] = src[t];
  }
  __syncthreads();

  const int wave = tid >> 6;
  const int lane = tid & 63;
  const int lr   = lane & 15;   // row-in-tile / M-row index
  const int g    = lane >> 4;   // k-group
  const int rowbase = blockIdx.x * 64 + wave * 16;

  // f B-fragments: lane holds f[rowbase+lr][32*ks + 8*g + j], j=0..7
  bf16x8 fb[2];
#pragma unroll
  for (int ks = 0; ks < 2; ++ks)
    fb[ks] = *(const bf16x8*)(fbf + (rowbase + lr) * 64 + ks * 32 + g * 8);

  const int e_clamp = (lr < 2) ? lr : 2;          // clamp address; rows e>=3 of D2 unread
  const bf16* w2base = w2s + e_clamp * 128 + g * 8;
  float* outrow = out + (size_t)(rowbase + lr) * 162;
  const f32x4 zero4 = {0.f, 0.f, 0.f, 0.f};

#pragma unroll 2
  for (int br = 0; br < 54; ++br) {
    const bf16* a1p = O1T + br * 8192 + lr * 64 + g * 8;
    bf16x8 a1[8][2];
#pragma unroll
    for (int mt = 0; mt < 8; ++mt)
#pragma unroll
      for (int ks = 0; ks < 2; ++ks)
        a1[mt][ks] = *(const bf16x8*)(a1p + mt * 1024 + ks * 32);

    f32x4 acc[8];
#pragma unroll
    for (int mt = 0; mt < 8; ++mt) {
      acc[mt] = __builtin_amdgcn_mfma_f32_16x16x32_bf16(a1[mt][0], fb[0], zero4, 0, 0, 0);
      acc[mt] = __builtin_amdgcn_mfma_f32_16x16x32_bf16(a1[mt][1], fb[1], acc[mt], 0, 0, 0);
    }

    // relu + pack: b2[s2][j] = h[32*s2 + 8*g + j][r]  (lane-local thanks to sigma)
    bf16x8 b2[4];
#pragma unroll
    for (int s2 = 0; s2 < 4; ++s2) {
      bf16x8 v;
#pragma unroll
      for (int t = 0; t < 4; ++t) v[t]     = (bf16)fmaxf(acc[2*s2][t], 0.f);
#pragma unroll
      for (int t = 0; t < 4; ++t) v[4 + t] = (bf16)fmaxf(acc[2*s2+1][t], 0.f);
      b2[s2] = v;
    }

    // layer 2: logits^T = W2^T * h^T
    const bf16* w2p = w2base + br * 384;
    f32x4 l2acc;
    {
      bf16x8 a2 = *(const bf16x8*)(w2p);
      l2acc = __builtin_amdgcn_mfma_f32_16x16x32_bf16(a2, b2[0], zero4, 0, 0, 0);
    }
#pragma unroll
    for (int s2 = 1; s2 < 4; ++s2) {
      bf16x8 a2 = *(const bf16x8*)(w2p + s2 * 32);
      l2acc = __builtin_amdgcn_mfma_f32_16x16x32_bf16(a2, b2[s2], l2acc, 0, 0, 0);
    }

    // softmax over 3 logits (valid in g==0 lanes; others compute garbage, unstored)
    const float b0 = Ob2[br * 3 + 0], b1 = Ob2[br * 3 + 1], b2s = Ob2[br * 3 + 2];
    float l0 = l2acc[0] + b0;
    float l1 = l2acc[1] + b1;
    float l2v = l2acc[2] + b2s;
    float m  = fmaxf(fmaxf(l0, l1), l2v);
    const float LOG2E = 1.4426950408889634f;
    float p0 = exp2f((l0 - m) * LOG2E);
    float p1 = exp2f((l1 - m) * LOG2E);
    float p2 = exp2f((l2v - m) * LOG2E);
    float rs = __builtin_amdgcn_rcpf(p0 + p1 + p2);
    if (g == 0) {
      float* o = outrow + br * 3;
      o[0] = p0 * rs; o[1] = p1 * rs; o[2] = p2 * rs;
    }
  }
}

// ---------------------------------------------------------------------------
extern "C" void kernel_launch(void* const* d_in, const int* in_sizes, int n_in,
                              void* d_out, int out_size, void* d_ws, size_t ws_size,
                              hipStream_t stream)
{
  (void)in_sizes; (void)n_in; (void)out_size; (void)ws_size;
  const float* x   = (const float*)d_in[0];
  const float* Cw1 = (const float*)d_in[1];
  const float* Cb1 = (const float*)d_in[2];
  const float* Cw2 = (const float*)d_in[3];
  const float* Cb2 = (const float*)d_in[4];
  const float* Nw1 = (const float*)d_in[5];
  const float* Nb1 = (const float*)d_in[6];
  const float* Nw2 = (const float*)d_in[7];
  const float* Nb2 = (const float*)d_in[8];
  const float* Fw1 = (const float*)d_in[9];
  const float* Fb1 = (const float*)d_in[10];
  const float* Fw2 = (const float*)d_in[11];
  const float* Fb2 = (const float*)d_in[12];
  const float* Ow1 = (const float*)d_in[13];
  const float* Ob1 = (const float*)d_in[14];
  const float* Ow2 = (const float*)d_in[15];
  const float* Ob2 = (const float*)d_in[16];

  char* ws = (char*)d_ws;
  bf16*  fbf  = (bf16*)(ws + 0);
  bf16*  O1T  = (bf16*)(ws + 8388608);
  bf16*  O2T  = (bf16*)(ws + 9273344);
  float* Cw1T = (float*)(ws + 9314816);
  float* Nw1T = (float*)(ws + 9316864);
  float* Fw1T = (float*)(ws + 9345536);
  float* Cw2p = (float*)(ws + 9376256);
  float* Nw2p = (float*)(ws + 9378304);
  float* Fw2p = (float*)(ws + 9406976);

  prep_kernel<<<1929, 256, 0, stream>>>(Ow1, Ob1, Ow2, Cw1, Nw1, Fw1, Cw2, Nw2, Fw2,
                                        O1T, O2T, Cw1T, Nw1T, Fw1T, Cw2p, Nw2p, Fw2p);
  mlp_cnf_kernel<<<512, 256, 0, stream>>>(x, Cw1T, Cb1, Cw2p, Cb2, Nw1T, Nb1, Nw2p, Nb2,
                                          Fw1T, Fb1, Fw2p, Fb2, fbf);
  heads_kernel<<<1024, 256, 0, stream>>>(fbf, O1T, O2T, Ob2, (float*)d_out);
}

// Round 2
// 423.075 us; speedup vs baseline: 1.4475x; 1.4475x over previous
//
#include <hip/hip_runtime.h>
#include <hip/hip_bf16.h>
#include <stdint.h>

typedef __bf16 bf16;
typedef bf16 bf16x8 __attribute__((ext_vector_type(8)));
typedef float f32x4 __attribute__((ext_vector_type(4)));

#define MFMA(a, b, c) __builtin_amdgcn_mfma_f32_16x16x32_bf16((a), (b), (c), 0, 0, 0)

// m(k): physical D-row delivered at B k-slot k by the standard b2-pack
// (verified by round-1 pass: inverse of O1T's sigma).
__device__ __forceinline__ int mk(int k) {
  return 32*(k>>5) + 16*((k>>2)&1) + 4*((k>>3)&3) + (k&3);
}

// ---------------------------------------------------------------------------
// Workspace layout (bytes):
//   fbf    @ 0        : [65536][64] bf16 (f padded, slot57=1.0)    8,388,608
//   O1T    @ 8388608  : [54][128][64] bf16 (perm rows, bias@k57)     884,736
//   O2T    @ 9273344  : [54][3][128] bf16                             41,472
//   blobG  @ 9314816  : mlp LDS blob, 71680 bf16 pre-swizzled        143,360
//   bias64 @ 9458176  : [64] f32  (Nb2|Cb2|1|0)                          256
//   Fb2pad @ 9458432  : [64] f32                                         256
//   tmp    @ 9458688  : [54][65536][3] f32 (optional)             42,467,328
// blob element offsets (bf16):
//   A1N_HI [128][64]@0      A1N_LO@8192    A1C_HI [128][32]@16384
//   A2N_HI [64][128]@20480  A2N_LO@28672   A2C_HI [16][128]@36864
//   A1F_HI [128][64]@38912  A1F_LO@47104   A2F_HI [64][128]@55296  A2F_LO@63488
// Each 16B chunk of a row is stored at chunk^(row&mask) (mask 7, A1C mask 3)
// so linear LDS staging lands bank-conflict-free fragments.
// ---------------------------------------------------------------------------

__global__ __launch_bounds__(256) void prep_kernel(
    const float* __restrict__ Cw1, const float* __restrict__ Cb1,
    const float* __restrict__ Cw2, const float* __restrict__ Cb2,
    const float* __restrict__ Nw1, const float* __restrict__ Nb1,
    const float* __restrict__ Nw2, const float* __restrict__ Nb2,
    const float* __restrict__ Fw1, const float* __restrict__ Fb1,
    const float* __restrict__ Fw2, const float* __restrict__ Fb2,
    const float* __restrict__ Ow1, const float* __restrict__ Ob1,
    const float* __restrict__ Ow2,
    bf16* __restrict__ O1T, bf16* __restrict__ O2T,
    bf16* __restrict__ blobG, float* __restrict__ bias64,
    float* __restrict__ Fb2pad)
{
  int gid = blockIdx.x * 256 + threadIdx.x;
  // O1T[br][m][k] = Ow1[br][k][sigma(m)] (k<57), Ob1[br][sigma(m)] (k==57), 0 else
  if (gid < 442368) {
    int k  = gid & 63;
    int m  = (gid >> 6) & 127;
    int br = gid >> 13;
    int c  = ((m >> 5) << 5) | (((m >> 2) & 3) << 3) | (((m >> 4) & 1) << 2) | (m & 3);
    float v = 0.f;
    if (k < 57)       v = Ow1[(br * 57 + k) * 128 + c];
    else if (k == 57) v = Ob1[br * 128 + c];
    O1T[gid] = (bf16)v;
    return;
  }
  gid -= 442368;
  // O2T[br][e][c] = Ow2[br][c][e]
  if (gid < 20736) {
    int br  = gid / 384;
    int rem = gid - br * 384;
    int e   = rem >> 7;
    int cc  = rem & 127;
    O2T[gid] = (bf16)Ow2[(br * 128 + cc) * 3 + e];
    return;
  }
  gid -= 20736;
  if (gid < 71680) {
    int idx = gid;
    float w = 0.f;
    bool lo = false;
    if (idx < 16384) {                       // A1N hi/lo [128 j][64 k]
      lo = idx >= 8192; int l = idx & 8191;
      int j = l >> 6, cp = l & 63;
      int k = (((cp >> 3) ^ (j & 7)) << 3) | (cp & 7);
      if (k < 54) w = Nw1[k * 128 + j];
      else if (k == 54) w = Nb1[j];
    } else if (idx < 20480) {                // A1C hi [128 j][32 kl] (slots 32+kl)
      int l = idx - 16384;
      int j = l >> 5, cp = l & 31;
      int kl = (((cp >> 3) ^ (j & 3)) << 3) | (cp & 7);
      int s = 32 + kl;
      if (s == 54) w = Cb1[j];
      else if (s >= 56 && s <= 59) w = Cw1[(s - 56) * 128 + j];
    } else if (idx < 36864) {                // A2N hi/lo [64 o][128 k]
      int l = idx - 20480; lo = l >= 8192; l &= 8191;
      int o = l >> 7, cp = l & 127;
      int k = (((cp >> 3) ^ (o & 7)) << 3) | (cp & 7);
      int p = mk(k);
      if (o < 54) w = Nw2[p * 54 + o];
    } else if (idx < 38912) {                // A2C16 hi [16 o'][128 k] (rows 48+o')
      int l = idx - 36864;
      int o = l >> 7, cp = l & 127;
      int k = (((cp >> 3) ^ (o & 7)) << 3) | (cp & 7);
      int p = mk(k);
      if (o >= 6 && o <= 8) w = Cw2[p * 3 + (o - 6)];
    } else if (idx < 55296) {                // A1F hi/lo [128 j][64 k]
      int l = idx - 38912; lo = l >= 8192; l &= 8191;
      int j = l >> 6, cp = l & 63;
      int k = (((cp >> 3) ^ (j & 7)) << 3) | (cp & 7);
      int p = mk(k);
      if (p < 54) w = Fw1[(3 + p) * 128 + j];
      else if (p < 57) w = Fw1[(p - 54) * 128 + j];
      else if (p == 57) w = Fb1[j];
    } else {                                 // A2F hi/lo [64 o][128 k]
      int l = idx - 55296; lo = l >= 8192; l &= 8191;
      int o = l >> 7, cp = l & 127;
      int k = (((cp >> 3) ^ (o & 7)) << 3) | (cp & 7);
      int p = mk(k);
      if (o < 57) w = Fw2[p * 57 + o];
    }
    bf16 h = (bf16)w;
    blobG[gid] = lo ? (bf16)(w - (float)h) : h;
    return;
  }
  gid -= 71680;
  if (gid < 64) {
    float v = 0.f;
    if (gid < 54) v = Nb2[gid];
    else if (gid < 57) v = Cb2[gid - 54];
    else if (gid == 57) v = 1.0f;            // constant-1 row -> F bias slot
    bias64[gid] = v;
    return;
  }
  gid -= 64;
  if (gid < 64) { Fb2pad[gid] = (gid < 57) ? Fb2[gid] : 0.f; return; }
}

// ---------------------------------------------------------------------------
// mlp kernel: C/N/F via bf16 hi/lo 3-pass MFMA (fp32-grade accuracy).
// Block = 512 thr = 8 waves; grid = 256 (1 block/CU); 256 rows/block.
// All weights staged once into 140KB LDS (pre-swizzled blob).
// ---------------------------------------------------------------------------
__global__ __launch_bounds__(512) void mlp_kernel(
    const float* __restrict__ x, const bf16* __restrict__ blobG,
    const float* __restrict__ bias64, const float* __restrict__ Fb2pad,
    bf16* __restrict__ fbf)
{
  __shared__ bf16 blob[71680];
  const int tid = threadIdx.x;
  {
    const uint4* src = (const uint4*)blobG;
    uint4* dst = (uint4*)blob;
    for (int t = tid; t < 8960; t += 512) dst[t] = src[t];
  }
  __syncthreads();

  const int wave = tid >> 6;
  const int lane = tid & 63;
  const int lr = lane & 15;
  const int g = lane >> 4;
  const f32x4 zero4 = {0.f, 0.f, 0.f, 0.f};

  auto frag = [&](int base, int stride, int row_, int chunk, int mask) -> bf16x8 {
    int c = chunk ^ (row_ & mask);
    return *(const bf16x8*)(blob + base + row_ * stride + c * 8);
  };

  for (int it = 0; it < 2; ++it) {
    const int row = blockIdx.x * 256 + (it * 8 + wave) * 16 + lr;
    const float* xr = x + (size_t)row * 58;

    // x B-fragments hi/lo. slots: 0-53 = x[4+s], 54 = 1.0, 56-59 = x[0..3], else 0
    bf16x8 bxh[2], bxl[2];
#pragma unroll
    for (int ks = 0; ks < 2; ++ks) {
#pragma unroll
      for (int u = 0; u < 8; ++u) {
        int s = ks * 32 + g * 8 + u;
        float v;
        if (s < 54) v = xr[4 + s];
        else if (s == 54) v = 1.0f;
        else if (s >= 56 && s <= 59) v = xr[s - 56];
        else v = 0.0f;
        bf16 h = (bf16)v;
        bxh[ks][u] = h;
        bxl[ks][u] = (bf16)(v - (float)h);
      }
    }

    // ---- layer 1: h_N[128], h_C[128] ----
    f32x4 accN[8], accC[8];
#pragma unroll
    for (int mt = 0; mt < 8; ++mt) {
      f32x4 a = zero4;
#pragma unroll
      for (int ks = 0; ks < 2; ++ks) {
        bf16x8 aH = frag(0,    64, mt * 16 + lr, ks * 4 + g, 7);
        bf16x8 aL = frag(8192, 64, mt * 16 + lr, ks * 4 + g, 7);
        a = MFMA(aH, bxh[ks], a);
        a = MFMA(aH, bxl[ks], a);
        a = MFMA(aL, bxh[ks], a);
      }
      accN[mt] = a;
      bf16x8 aC = frag(16384, 32, mt * 16 + lr, g, 3);
      f32x4 c = MFMA(aC, bxh[1], zero4);
      c = MFMA(aC, bxl[1], c);
      accC[mt] = c;
    }

    // relu + hi/lo split-pack
    bf16x8 b2nh[4], b2nl[4], b2ch[4], b2cl[4];
#pragma unroll
    for (int s = 0; s < 4; ++s) {
#pragma unroll
      for (int u = 0; u < 8; ++u) {
        float vN = fmaxf(accN[2 * s + (u >> 2)][u & 3], 0.f);
        bf16 hN = (bf16)vN;
        b2nh[s][u] = hN;
        b2nl[s][u] = (bf16)(vN - (float)hN);
        float vC = fmaxf(accC[2 * s + (u >> 2)][u & 3], 0.f);
        bf16 hC = (bf16)vC;
        b2ch[s][u] = hC;
        b2cl[s][u] = (bf16)(vC - (float)hC);
      }
    }

    // ---- layer 2 combined: D2 = [n(54); c(3); 1; 0...] ----
    f32x4 acc2[4];
#pragma unroll
    for (int mt = 0; mt < 4; ++mt) {
      f32x4 a = *(const f32x4*)(bias64 + mt * 16 + 4 * g);
#pragma unroll
      for (int ks = 0; ks < 4; ++ks) {
        bf16x8 aH = frag(20480, 128, mt * 16 + lr, ks * 4 + g, 7);
        bf16x8 aL = frag(28672, 128, mt * 16 + lr, ks * 4 + g, 7);
        a = MFMA(aH, b2nh[ks], a);
        a = MFMA(aH, b2nl[ks], a);
        a = MFMA(aL, b2nh[ks], a);
      }
      acc2[mt] = a;
    }
#pragma unroll
    for (int ks = 0; ks < 4; ++ks) {
      bf16x8 aC = frag(36864, 128, lr, ks * 4 + g, 7);
      acc2[3] = MFMA(aC, b2ch[ks], acc2[3]);
      acc2[3] = MFMA(aC, b2cl[ks], acc2[3]);
    }

    // split (no relu) -> F input frags
    bf16x8 b2fh[2], b2fl[2];
#pragma unroll
    for (int s = 0; s < 2; ++s) {
#pragma unroll
      for (int u = 0; u < 8; ++u) {
        float v = acc2[2 * s + (u >> 2)][u & 3];
        bf16 h = (bf16)v;
        b2fh[s][u] = h;
        b2fl[s][u] = (bf16)(v - (float)h);
      }
    }

    // ---- F layer 1 ----
    f32x4 accF[8];
#pragma unroll
    for (int mt = 0; mt < 8; ++mt) {
      f32x4 a = zero4;
#pragma unroll
      for (int ks = 0; ks < 2; ++ks) {
        bf16x8 aH = frag(38912, 64, mt * 16 + lr, ks * 4 + g, 7);
        bf16x8 aL = frag(47104, 64, mt * 16 + lr, ks * 4 + g, 7);
        a = MFMA(aH, b2fh[ks], a);
        a = MFMA(aH, b2fl[ks], a);
        a = MFMA(aL, b2fh[ks], a);
      }
      accF[mt] = a;
    }
    bf16x8 bHh[4], bHl[4];
#pragma unroll
    for (int s = 0; s < 4; ++s) {
#pragma unroll
      for (int u = 0; u < 8; ++u) {
        float v = fmaxf(accF[2 * s + (u >> 2)][u & 3], 0.f);
        bf16 h = (bf16)v;
        bHh[s][u] = h;
        bHl[s][u] = (bf16)(v - (float)h);
      }
    }

    // ---- F layer 2 -> f[64] ----
    f32x4 accO[4];
#pragma unroll
    for (int mt = 0; mt < 4; ++mt) {
      f32x4 a = *(const f32x4*)(Fb2pad + mt * 16 + 4 * g);
#pragma unroll
      for (int ks = 0; ks < 4; ++ks) {
        bf16x8 aH = frag(55296, 128, mt * 16 + lr, ks * 4 + g, 7);
        bf16x8 aL = frag(63488, 128, mt * 16 + lr, ks * 4 + g, 7);
        a = MFMA(aH, bHh[ks], a);
        a = MFMA(aH, bHl[ks], a);
        a = MFMA(aL, bHh[ks], a);
      }
      accO[mt] = a;
    }
    if (g == 2) accO[3][1] = 1.0f;  // f slot 57 = 1.0 (heads bias trick)

    // store f row (bf16, natural slot order)
#pragma unroll
    for (int mt = 0; mt < 4; ++mt) {
      uint32_t w0 = (uint32_t)__builtin_bit_cast(uint16_t, (bf16)accO[mt][0]) |
                    ((uint32_t)__builtin_bit_cast(uint16_t, (bf16)accO[mt][1]) << 16);
      uint32_t w1 = (uint32_t)__builtin_bit_cast(uint16_t, (bf16)accO[mt][2]) |
                    ((uint32_t)__builtin_bit_cast(uint16_t, (bf16)accO[mt][3]) << 16);
      *(uint2*)(fbf + (size_t)row * 64 + mt * 16 + 4 * g) = make_uint2(w0, w1);
    }
  }
}

// ---------------------------------------------------------------------------
// heads v3: wave = one branch, weights in VGPRs (loaded once), stream rows.
// Grid = 54 branches x 64 chunks (br-major within chunk window for L2 reuse).
// Block = 64 thr = 1 wave; 1024 rows per wave (64 tiles of 16).
// ---------------------------------------------------------------------------
template<bool USE_TMP>
__global__ __launch_bounds__(64, 3) void heads_kernel(
    const bf16* __restrict__ fbf, const bf16* __restrict__ O1T,
    const bf16* __restrict__ O2T, const float* __restrict__ Ob2,
    float* __restrict__ tmp, float* __restrict__ out)
{
  const int bid = blockIdx.x;
  const int br = bid % 54;
  const int chunk = bid / 54;
  const int lane = threadIdx.x;
  const int lr = lane & 15;
  const int g = lane >> 4;
  const f32x4 zero4 = {0.f, 0.f, 0.f, 0.f};

  // branch weights -> registers (once)
  const bf16* a1p = O1T + br * 8192 + lr * 64 + g * 8;
  bf16x8 a1[8][2];
#pragma unroll
  for (int mt = 0; mt < 8; ++mt)
#pragma unroll
    for (int ks = 0; ks < 2; ++ks)
      a1[mt][ks] = *(const bf16x8*)(a1p + mt * 1024 + ks * 32);

  const int e_clamp = (lr < 2) ? lr : 2;
  const bf16* w2p = O2T + br * 384 + e_clamp * 128 + g * 8;
  bf16x8 w2[4];
#pragma unroll
  for (int s2 = 0; s2 < 4; ++s2) w2[s2] = *(const bf16x8*)(w2p + s2 * 32);

  const float b0 = Ob2[br * 3 + 0], b1 = Ob2[br * 3 + 1], b2s = Ob2[br * 3 + 2];
  const float LOG2E = 1.4426950408889634f;

#pragma unroll 2
  for (int it = 0; it < 64; ++it) {
    const int row = chunk * 1024 + it * 16 + lr;
    const bf16* fp = fbf + (size_t)row * 64 + g * 8;
    bf16x8 fb0 = *(const bf16x8*)(fp);
    bf16x8 fb1 = *(const bf16x8*)(fp + 32);

    f32x4 acc[8];
#pragma unroll
    for (int mt = 0; mt < 8; ++mt) {
      acc[mt] = MFMA(a1[mt][0], fb0, zero4);
      acc[mt] = MFMA(a1[mt][1], fb1, acc[mt]);
    }

    bf16x8 b2[4];
#pragma unroll
    for (int s2 = 0; s2 < 4; ++s2) {
#pragma unroll
      for (int t = 0; t < 4; ++t) b2[s2][t]     = (bf16)fmaxf(acc[2 * s2][t], 0.f);
#pragma unroll
      for (int t = 0; t < 4; ++t) b2[s2][4 + t] = (bf16)fmaxf(acc[2 * s2 + 1][t], 0.f);
    }

    f32x4 l2 = MFMA(w2[0], b2[0], zero4);
#pragma unroll
    for (int s2 = 1; s2 < 4; ++s2) l2 = MFMA(w2[s2], b2[s2], l2);

    float l0 = l2[0] + b0;
    float l1 = l2[1] + b1;
    float lv = l2[2] + b2s;
    float m = fmaxf(fmaxf(l0, l1), lv);
    float p0 = exp2f((l0 - m) * LOG2E);
    float p1 = exp2f((l1 - m) * LOG2E);
    float p2 = exp2f((lv - m) * LOG2E);
    float rs = __builtin_amdgcn_rcpf(p0 + p1 + p2);
    if (g == 0) {
      if (USE_TMP) {
        float* tp = tmp + ((size_t)br * 65536 + row) * 3;
        tp[0] = p0 * rs; tp[1] = p1 * rs; tp[2] = p2 * rs;
      } else {
        float* op = out + (size_t)row * 162 + br * 3;
        op[0] = p0 * rs; op[1] = p1 * rs; op[2] = p2 * rs;
      }
    }
  }
}

// ---------------------------------------------------------------------------
// transpose: tmp[54][65536][3] -> out[65536][162], coalesced both sides.
// ---------------------------------------------------------------------------
__global__ __launch_bounds__(256) void transpose_kernel(
    const float* __restrict__ tmp, float* __restrict__ out)
{
  __shared__ float sh[64 * 163];
  const int tid = threadIdx.x;
  const int rowbase = blockIdx.x * 64;
  for (int t = tid; t < 10368; t += 256) {
    int p = t / 192;
    int q = t - p * 192;
    int r = q / 3;
    int e = q - r * 3;
    sh[r * 163 + p * 3 + e] = tmp[((size_t)p * 65536 + rowbase + r) * 3 + e];
  }
  __syncthreads();
  for (int t = tid; t < 10368; t += 256) {
    int r = t / 162;
    int c = t - r * 162;
    out[(size_t)(rowbase + r) * 162 + c] = sh[r * 163 + c];
  }
}

// ---------------------------------------------------------------------------
extern "C" void kernel_launch(void* const* d_in, const int* in_sizes, int n_in,
                              void* d_out, int out_size, void* d_ws, size_t ws_size,
                              hipStream_t stream)
{
  (void)in_sizes; (void)n_in; (void)out_size;
  const float* x   = (const float*)d_in[0];
  const float* Cw1 = (const float*)d_in[1];
  const float* Cb1 = (const float*)d_in[2];
  const float* Cw2 = (const float*)d_in[3];
  const float* Cb2 = (const float*)d_in[4];
  const float* Nw1 = (const float*)d_in[5];
  const float* Nb1 = (const float*)d_in[6];
  const float* Nw2 = (const float*)d_in[7];
  const float* Nb2 = (const float*)d_in[8];
  const float* Fw1 = (const float*)d_in[9];
  const float* Fb1 = (const float*)d_in[10];
  const float* Fw2 = (const float*)d_in[11];
  const float* Fb2 = (const float*)d_in[12];
  const float* Ow1 = (const float*)d_in[13];
  const float* Ob1 = (const float*)d_in[14];
  const float* Ow2 = (const float*)d_in[15];
  const float* Ob2 = (const float*)d_in[16];

  char* ws = (char*)d_ws;
  bf16*  fbf    = (bf16*)(ws + 0);
  bf16*  O1T    = (bf16*)(ws + 8388608);
  bf16*  O2T    = (bf16*)(ws + 9273344);
  bf16*  blobG  = (bf16*)(ws + 9314816);
  float* bias64 = (float*)(ws + 9458176);
  float* Fb2pad = (float*)(ws + 9458432);
  float* tmp    = (float*)(ws + 9458688);
  const size_t need = 9458688ull + 42467328ull;
  const bool useTmp = ws_size >= need;

  prep_kernel<<<2090, 256, 0, stream>>>(Cw1, Cb1, Cw2, Cb2, Nw1, Nb1, Nw2, Nb2,
                                        Fw1, Fb1, Fw2, Fb2, Ow1, Ob1, Ow2,
                                        O1T, O2T, blobG, bias64, Fb2pad);
  mlp_kernel<<<256, 512, 0, stream>>>(x, blobG, bias64, Fb2pad, fbf);
  if (useTmp) {
    heads_kernel<true><<<3456, 64, 0, stream>>>(fbf, O1T, O2T, Ob2, tmp, (float*)d_out);
    transpose_kernel<<<1024, 256, 0, stream>>>(tmp, (float*)d_out);
  } else {
    heads_kernel<false><<<3456, 64, 0, stream>>>(fbf, O1T, O2T, Ob2, tmp, (float*)d_out);
  }
}